// Round 2
// baseline (799.730 us; speedup 1.0000x reference)
//
#include <hip/hip_runtime.h>
#include <math.h>

#define D_DIM 4096
#define E_DIM 64
#define NCOL 128      // route(64) + noise(64) output columns
#define BK 32
#define TPB 32        // tokens per block
#define KTOP 8
#define TAU 1e-3f     // ambiguity threshold: >> worst-case fp32 accum error (1.6e-4)

__global__ void zero_cnt(unsigned int* c) { *c = 0u; }

// ---------------- Pass 1: fp32 GEMM + epilogue + flagging ----------------
// As: [BK][32 tokens] padded stride 34; Bs: [BK][128 cols] padded stride 132
__global__ __launch_bounds__(256, 2)
void noisy_topk_router(const float* __restrict__ mh,
                       const float* __restrict__ Wr,
                       const float* __restrict__ br,
                       const float* __restrict__ Wn,
                       const float* __restrict__ bn,
                       const float* __restrict__ eps,
                       float* __restrict__ out_probs,
                       float* __restrict__ out_idx,
                       unsigned int* __restrict__ cnt,
                       int* __restrict__ list)
{
    __shared__ float As[BK * 34];
    __shared__ float Bs[BK * 132];
    __shared__ float zs[TPB * NCOL];
    __shared__ float ns[TPB * E_DIM];

    const int tid  = threadIdx.x;
    const int tok0 = blockIdx.x * TPB;

    const int at  = tid >> 3;          // 0..31
    const int akq = (tid & 7) << 2;    // 0,4,...,28
    const float* aptr = mh + (size_t)(tok0 + at) * D_DIM + akq;

    const float* bptr[4];
    int bwr[4];
    #pragma unroll
    for (int q = 0; q < 4; ++q) {
        int fid = tid + 256 * q;
        int e   = fid >> 3;
        int kq  = (fid & 7) << 2;
        const float* base = (e < E_DIM) ? (Wr + (size_t)e * D_DIM)
                                        : (Wn + (size_t)(e - E_DIM) * D_DIM);
        bptr[q] = base + kq;
        bwr[q]  = kq * 132 + e;
    }

    const int r0 = (tid >> 4) << 1;
    const int c0 = (tid & 15) << 3;

    float acc[2][8];
    #pragma unroll
    for (int i = 0; i < 2; ++i)
        #pragma unroll
        for (int j = 0; j < 8; ++j) acc[i][j] = 0.f;

    for (int k0 = 0; k0 < D_DIM; k0 += BK) {
        __syncthreads();
        float4 av = *(const float4*)(aptr + k0);
        As[(akq + 0) * 34 + at] = av.x;
        As[(akq + 1) * 34 + at] = av.y;
        As[(akq + 2) * 34 + at] = av.z;
        As[(akq + 3) * 34 + at] = av.w;
        #pragma unroll
        for (int q = 0; q < 4; ++q) {
            float4 bv = *(const float4*)(bptr[q] + k0);
            Bs[bwr[q] + 0 * 132] = bv.x;
            Bs[bwr[q] + 1 * 132] = bv.y;
            Bs[bwr[q] + 2 * 132] = bv.z;
            Bs[bwr[q] + 3 * 132] = bv.w;
        }
        __syncthreads();

        #pragma unroll
        for (int kk = 0; kk < BK; ++kk) {
            float2 a  = *(const float2*)&As[kk * 34 + r0];
            float4 b0 = *(const float4*)&Bs[kk * 132 + c0];
            float4 b1 = *(const float4*)&Bs[kk * 132 + c0 + 4];
            float aa[2] = {a.x, a.y};
            float bb[8] = {b0.x, b0.y, b0.z, b0.w, b1.x, b1.y, b1.z, b1.w};
            #pragma unroll
            for (int i = 0; i < 2; ++i)
                #pragma unroll
                for (int j = 0; j < 8; ++j)
                    acc[i][j] = fmaf(aa[i], bb[j], acc[i][j]);
        }
    }

    #pragma unroll
    for (int j = 0; j < 8; ++j) {
        int c = c0 + j;
        float bias = (c < E_DIM) ? br[c] : bn[c - E_DIM];
        zs[(r0 + 0) * NCOL + c] = acc[0][j] + bias;
        zs[(r0 + 1) * NCOL + c] = acc[1][j] + bias;
    }
    __syncthreads();

    {
        int t  = tid >> 3;
        int e0 = (tid & 7) << 3;
        const float* ep = eps + (size_t)(tok0 + t) * E_DIM + e0;
        #pragma unroll
        for (int j = 0; j < 8; ++j) {
            float zr = zs[t * NCOL + e0 + j];
            float zn = zs[t * NCOL + E_DIM + e0 + j];
            float sp = fmaxf(zn, 0.f) + log1pf(expf(-fabsf(zn)));
            ns[t * E_DIM + e0 + j] = zr + ep[j] * sp;
        }
    }
    __syncthreads();

    // top-8 (+9th for gap check) + masked softmax: one wave per 8 tokens
    {
        int wv   = tid >> 6;
        int lane = tid & 63;
        for (int tk = 0; tk < 8; ++tk) {
            int t = wv * 8 + tk;
            float v0 = ns[t * E_DIM + lane];
            float v  = v0;
            float m0 = 0.f, denom = 0.f, prev = 0.f, mingap = INFINITY;
            bool selected = false;
            int rankedIdx = 0;
            #pragma unroll
            for (int k = 0; k < KTOP + 1; ++k) {
                float mv = v; int mi = lane;
                #pragma unroll
                for (int off = 32; off > 0; off >>= 1) {
                    float ov = __shfl_xor(mv, off);
                    int   oi = __shfl_xor(mi, off);
                    if (ov > mv || (ov == mv && oi < mi)) { mv = ov; mi = oi; }
                }
                if (k == 0) m0 = mv; else mingap = fminf(mingap, prev - mv);
                prev = mv;
                if (k < KTOP) {
                    denom += expf(mv - m0);
                    if (lane == mi) { selected = true; v = -INFINITY; }
                    if (lane == k) rankedIdx = mi;
                }
            }
            float p = selected ? expf(v0 - m0) / denom : 0.f;
            size_t tg = (size_t)(tok0 + t);
            out_probs[tg * E_DIM + lane] = p;
            if (lane < KTOP) out_idx[tg * KTOP + lane] = (float)rankedIdx;
            if (mingap < TAU && lane == 0) {
                unsigned int w = atomicAdd(cnt, 1u);
                list[w] = (int)tg;
            }
        }
    }
}

// ---------------- Pass 2: fp64 exact recompute for flagged tokens ----------------
// One wave per token; lane = expert. Each lane owns W_route[lane] and
// W_noise[lane] rows; mh row is a wave-broadcast read.
__global__ __launch_bounds__(256)
void refine_fp64(const float* __restrict__ mh,
                 const float* __restrict__ Wr,
                 const float* __restrict__ br,
                 const float* __restrict__ Wn,
                 const float* __restrict__ bn,
                 const float* __restrict__ eps,
                 float* __restrict__ out_probs,
                 float* __restrict__ out_idx,
                 const unsigned int* __restrict__ cnt,
                 const int* __restrict__ list)
{
    const unsigned int n = *cnt;
    const int lane = threadIdx.x & 63;
    const int wv   = threadIdx.x >> 6;

    for (unsigned int g = blockIdx.x; g * 4 < n; g += gridDim.x) {
        unsigned int li = g * 4 + wv;
        if (li >= n) continue;
        int tok = list[li];

        const float* x  = mh + (size_t)tok * D_DIM;
        const float* wr = Wr + (size_t)lane * D_DIM;
        const float* wn = Wn + (size_t)lane * D_DIM;
        double sr = 0.0, sn = 0.0;
        for (int k = 0; k < D_DIM; k += 4) {
            float4 xv = *(const float4*)(x + k);
            float4 rv = *(const float4*)(wr + k);
            float4 nv = *(const float4*)(wn + k);
            sr += (double)xv.x * (double)rv.x;
            sr += (double)xv.y * (double)rv.y;
            sr += (double)xv.z * (double)rv.z;
            sr += (double)xv.w * (double)rv.w;
            sn += (double)xv.x * (double)nv.x;
            sn += (double)xv.y * (double)nv.y;
            sn += (double)xv.z * (double)nv.z;
            sn += (double)xv.w * (double)nv.w;
        }
        double zr = sr + (double)br[lane];
        double zn = sn + (double)bn[lane];
        double sp = fmax(zn, 0.0) + log1p(exp(-fabs(zn)));
        double nl = zr + (double)eps[(size_t)tok * E_DIM + lane] * sp;

        double v = nl, m0 = 0.0, denom = 0.0;
        bool selected = false;
        int rankedIdx = 0;
        #pragma unroll
        for (int k = 0; k < KTOP; ++k) {
            double mv = v; int mi = lane;
            #pragma unroll
            for (int off = 32; off > 0; off >>= 1) {
                double ov = __shfl_xor(mv, off);
                int    oi = __shfl_xor(mi, off);
                if (ov > mv || (ov == mv && oi < mi)) { mv = ov; mi = oi; }
            }
            if (k == 0) m0 = mv;
            denom += exp(mv - m0);
            if (lane == mi) { selected = true; v = -INFINITY; }
            if (lane == k) rankedIdx = mi;
        }
        float p = selected ? (float)(exp(nl - m0) / denom) : 0.f;
        out_probs[(size_t)tok * E_DIM + lane] = p;
        if (lane < KTOP) out_idx[(size_t)tok * KTOP + lane] = (float)rankedIdx;
    }
}

extern "C" void kernel_launch(void* const* d_in, const int* in_sizes, int n_in,
                              void* d_out, int out_size, void* d_ws, size_t ws_size,
                              hipStream_t stream) {
    const float* mh  = (const float*)d_in[0];
    const float* Wr  = (const float*)d_in[1];
    const float* br  = (const float*)d_in[2];
    const float* Wn  = (const float*)d_in[3];
    const float* bn  = (const float*)d_in[4];
    const float* eps = (const float*)d_in[5];

    const int ntok = in_sizes[0] / D_DIM;   // 16384
    float* out_probs = (float*)d_out;                        // [ntok][64]
    float* out_idx   = (float*)d_out + (size_t)ntok * E_DIM; // [ntok][8] as float

    unsigned int* cnt = (unsigned int*)d_ws;
    int* list = (int*)((char*)d_ws + 16);

    hipLaunchKernelGGL(zero_cnt, dim3(1), dim3(1), 0, stream, cnt);
    hipLaunchKernelGGL(noisy_topk_router, dim3(ntok / TPB), dim3(256), 0, stream,
                       mh, Wr, br, Wn, bn, eps, out_probs, out_idx, cnt, list);
    hipLaunchKernelGGL(refine_fp64, dim3(512), dim3(256), 0, stream,
                       mh, Wr, br, Wn, bn, eps, out_probs, out_idx, cnt, list);
}

// Round 3
// 798.423 us; speedup vs baseline: 1.0016x; 1.0016x over previous
//
#include <hip/hip_runtime.h>
#include <math.h>

#define D_DIM 4096
#define E_DIM 64
#define NCOL 128      // route(64) + noise(64) output columns
#define BK 32
#define TPB 32        // tokens per block
#define KTOP 8
#define TAU 1e-3f     // ambiguity threshold: >> worst-case fp32 accum error (1.6e-4)

__global__ void zero_cnt(unsigned int* c) { *c = 0u; }

// ---------------- Pass 1: fp32 GEMM + epilogue + flagging ----------------
// As: [BK][32 tokens] padded stride 34; Bs: [BK][128 cols] padded stride 132
__global__ __launch_bounds__(256, 2)
void noisy_topk_router(const float* __restrict__ mh,
                       const float* __restrict__ Wr,
                       const float* __restrict__ br,
                       const float* __restrict__ Wn,
                       const float* __restrict__ bn,
                       const float* __restrict__ eps,
                       float* __restrict__ out_probs,
                       float* __restrict__ out_idx,
                       unsigned int* __restrict__ cnt,
                       int* __restrict__ list)
{
    __shared__ float As[BK * 34];
    __shared__ float Bs[BK * 132];
    __shared__ float zs[TPB * NCOL];
    __shared__ float ns[TPB * E_DIM];

    const int tid  = threadIdx.x;
    const int tok0 = blockIdx.x * TPB;

    const int at  = tid >> 3;          // 0..31
    const int akq = (tid & 7) << 2;    // 0,4,...,28
    const float* aptr = mh + (size_t)(tok0 + at) * D_DIM + akq;

    const float* bptr[4];
    int bwr[4];
    #pragma unroll
    for (int q = 0; q < 4; ++q) {
        int fid = tid + 256 * q;
        int e   = fid >> 3;
        int kq  = (fid & 7) << 2;
        const float* base = (e < E_DIM) ? (Wr + (size_t)e * D_DIM)
                                        : (Wn + (size_t)(e - E_DIM) * D_DIM);
        bptr[q] = base + kq;
        bwr[q]  = kq * 132 + e;
    }

    const int r0 = (tid >> 4) << 1;
    const int c0 = (tid & 15) << 3;

    float acc[2][8];
    #pragma unroll
    for (int i = 0; i < 2; ++i)
        #pragma unroll
        for (int j = 0; j < 8; ++j) acc[i][j] = 0.f;

    for (int k0 = 0; k0 < D_DIM; k0 += BK) {
        __syncthreads();
        float4 av = *(const float4*)(aptr + k0);
        As[(akq + 0) * 34 + at] = av.x;
        As[(akq + 1) * 34 + at] = av.y;
        As[(akq + 2) * 34 + at] = av.z;
        As[(akq + 3) * 34 + at] = av.w;
        #pragma unroll
        for (int q = 0; q < 4; ++q) {
            float4 bv = *(const float4*)(bptr[q] + k0);
            Bs[bwr[q] + 0 * 132] = bv.x;
            Bs[bwr[q] + 1 * 132] = bv.y;
            Bs[bwr[q] + 2 * 132] = bv.z;
            Bs[bwr[q] + 3 * 132] = bv.w;
        }
        __syncthreads();

        #pragma unroll
        for (int kk = 0; kk < BK; ++kk) {
            float2 a  = *(const float2*)&As[kk * 34 + r0];
            float4 b0 = *(const float4*)&Bs[kk * 132 + c0];
            float4 b1 = *(const float4*)&Bs[kk * 132 + c0 + 4];
            float aa[2] = {a.x, a.y};
            float bb[8] = {b0.x, b0.y, b0.z, b0.w, b1.x, b1.y, b1.z, b1.w};
            #pragma unroll
            for (int i = 0; i < 2; ++i)
                #pragma unroll
                for (int j = 0; j < 8; ++j)
                    acc[i][j] = fmaf(aa[i], bb[j], acc[i][j]);
        }
    }

    #pragma unroll
    for (int j = 0; j < 8; ++j) {
        int c = c0 + j;
        float bias = (c < E_DIM) ? br[c] : bn[c - E_DIM];
        zs[(r0 + 0) * NCOL + c] = acc[0][j] + bias;
        zs[(r0 + 1) * NCOL + c] = acc[1][j] + bias;
    }
    __syncthreads();

    {
        int t  = tid >> 3;
        int e0 = (tid & 7) << 3;
        const float* ep = eps + (size_t)(tok0 + t) * E_DIM + e0;
        #pragma unroll
        for (int j = 0; j < 8; ++j) {
            float zr = zs[t * NCOL + e0 + j];
            float zn = zs[t * NCOL + E_DIM + e0 + j];
            float sp = fmaxf(zn, 0.f) + log1pf(expf(-fabsf(zn)));
            ns[t * E_DIM + e0 + j] = zr + ep[j] * sp;
        }
    }
    __syncthreads();

    // top-8 (+9th for gap check) + masked softmax: one wave per 8 tokens
    {
        int wv   = tid >> 6;
        int lane = tid & 63;
        for (int tk = 0; tk < 8; ++tk) {
            int t = wv * 8 + tk;
            float v0 = ns[t * E_DIM + lane];
            float v  = v0;
            float m0 = 0.f, denom = 0.f, prev = 0.f, mingap = INFINITY;
            bool selected = false;
            int rankedIdx = 0;
            #pragma unroll
            for (int k = 0; k < KTOP + 1; ++k) {
                float mv = v; int mi = lane;
                #pragma unroll
                for (int off = 32; off > 0; off >>= 1) {
                    float ov = __shfl_xor(mv, off);
                    int   oi = __shfl_xor(mi, off);
                    if (ov > mv || (ov == mv && oi < mi)) { mv = ov; mi = oi; }
                }
                if (k == 0) m0 = mv; else mingap = fminf(mingap, prev - mv);
                prev = mv;
                if (k < KTOP) {
                    denom += expf(mv - m0);
                    if (lane == mi) { selected = true; v = -INFINITY; }
                    if (lane == k) rankedIdx = mi;
                }
            }
            float p = selected ? expf(v0 - m0) / denom : 0.f;
            size_t tg = (size_t)(tok0 + t);
            out_probs[tg * E_DIM + lane] = p;
            if (lane < KTOP) out_idx[tg * KTOP + lane] = (float)rankedIdx;
            if (mingap < TAU && lane == 0) {
                unsigned int w = atomicAdd(cnt, 1u);
                list[w] = (int)tg;
            }
        }
    }
}

// ---------------- Pass 2: fp64 exact recompute for flagged tokens ----------------
// One wave per token; lane = expert. Each lane owns W_route[lane] and
// W_noise[lane] rows; mh row is a wave-broadcast read.
__global__ __launch_bounds__(256)
void refine_fp64(const float* __restrict__ mh,
                 const float* __restrict__ Wr,
                 const float* __restrict__ br,
                 const float* __restrict__ Wn,
                 const float* __restrict__ bn,
                 const float* __restrict__ eps,
                 float* __restrict__ out_probs,
                 float* __restrict__ out_idx,
                 const unsigned int* __restrict__ cnt,
                 const int* __restrict__ list)
{
    const unsigned int n = *cnt;
    const int lane = threadIdx.x & 63;
    const int wv   = threadIdx.x >> 6;

    for (unsigned int g = blockIdx.x; g * 4 < n; g += gridDim.x) {
        unsigned int li = g * 4 + wv;
        if (li >= n) continue;
        int tok = list[li];

        const float* x  = mh + (size_t)tok * D_DIM;
        const float* wr = Wr + (size_t)lane * D_DIM;
        const float* wn = Wn + (size_t)lane * D_DIM;
        double sr = 0.0, sn = 0.0;
        for (int k = 0; k < D_DIM; k += 4) {
            float4 xv = *(const float4*)(x + k);
            float4 rv = *(const float4*)(wr + k);
            float4 nv = *(const float4*)(wn + k);
            sr += (double)xv.x * (double)rv.x;
            sr += (double)xv.y * (double)rv.y;
            sr += (double)xv.z * (double)rv.z;
            sr += (double)xv.w * (double)rv.w;
            sn += (double)xv.x * (double)nv.x;
            sn += (double)xv.y * (double)nv.y;
            sn += (double)xv.z * (double)nv.z;
            sn += (double)xv.w * (double)nv.w;
        }
        double zr = sr + (double)br[lane];
        double zn = sn + (double)bn[lane];
        double sp = fmax(zn, 0.0) + log1p(exp(-fabs(zn)));
        double nl = zr + (double)eps[(size_t)tok * E_DIM + lane] * sp;

        double v = nl, m0 = 0.0, denom = 0.0;
        bool selected = false;
        int rankedIdx = 0;
        #pragma unroll
        for (int k = 0; k < KTOP; ++k) {
            double mv = v; int mi = lane;
            #pragma unroll
            for (int off = 32; off > 0; off >>= 1) {
                double ov = __shfl_xor(mv, off);
                int    oi = __shfl_xor(mi, off);
                if (ov > mv || (ov == mv && oi < mi)) { mv = ov; mi = oi; }
            }
            if (k == 0) m0 = mv;
            denom += exp(mv - m0);
            if (lane == mi) { selected = true; v = -INFINITY; }
            if (lane == k) rankedIdx = mi;
        }
        float p = selected ? (float)(exp(nl - m0) / denom) : 0.f;
        out_probs[(size_t)tok * E_DIM + lane] = p;
        if (lane < KTOP) out_idx[(size_t)tok * KTOP + lane] = (float)rankedIdx;
    }
}

extern "C" void kernel_launch(void* const* d_in, const int* in_sizes, int n_in,
                              void* d_out, int out_size, void* d_ws, size_t ws_size,
                              hipStream_t stream) {
    const float* mh  = (const float*)d_in[0];
    const float* Wr  = (const float*)d_in[1];
    const float* br  = (const float*)d_in[2];
    const float* Wn  = (const float*)d_in[3];
    const float* bn  = (const float*)d_in[4];
    const float* eps = (const float*)d_in[5];

    const int ntok = in_sizes[0] / D_DIM;   // 16384
    float* out_probs = (float*)d_out;                        // [ntok][64]
    float* out_idx   = (float*)d_out + (size_t)ntok * E_DIM; // [ntok][8] as float

    unsigned int* cnt = (unsigned int*)d_ws;
    int* list = (int*)((char*)d_ws + 16);

    hipLaunchKernelGGL(zero_cnt, dim3(1), dim3(1), 0, stream, cnt);
    hipLaunchKernelGGL(noisy_topk_router, dim3(ntok / TPB), dim3(256), 0, stream,
                       mh, Wr, br, Wn, bn, eps, out_probs, out_idx, cnt, list);
    hipLaunchKernelGGL(refine_fp64, dim3(512), dim3(256), 0, stream,
                       mh, Wr, br, Wn, bn, eps, out_probs, out_idx, cnt, list);
}

// Round 4
// 797.659 us; speedup vs baseline: 1.0026x; 1.0010x over previous
//
#include <hip/hip_runtime.h>
#include <math.h>

#define D_DIM 4096
#define E_DIM 64
#define NCOL 128      // route(64) + noise(64) output columns
#define BK 32
#define TPB 32        // tokens per block
#define KTOP 8
#define TAU 1e-3f     // ambiguity threshold: >> worst-case fp32 accum error (1.6e-4)

__global__ void zero_cnt(unsigned int* c) { *c = 0u; }

// ---------------- Pass 1: fp32 GEMM + epilogue + flagging ----------------
// As: [BK][32 tokens] padded stride 34; Bs: [BK][128 cols] padded stride 132
__global__ __launch_bounds__(256, 2)
void noisy_topk_router(const float* __restrict__ mh,
                       const float* __restrict__ Wr,
                       const float* __restrict__ br,
                       const float* __restrict__ Wn,
                       const float* __restrict__ bn,
                       const float* __restrict__ eps,
                       float* __restrict__ out_probs,
                       float* __restrict__ out_idx,
                       unsigned int* __restrict__ cnt,
                       int* __restrict__ list)
{
    __shared__ float As[BK * 34];
    __shared__ float Bs[BK * 132];
    __shared__ float zs[TPB * NCOL];
    __shared__ float ns[TPB * E_DIM];

    const int tid  = threadIdx.x;
    const int tok0 = blockIdx.x * TPB;

    const int at  = tid >> 3;          // 0..31
    const int akq = (tid & 7) << 2;    // 0,4,...,28
    const float* aptr = mh + (size_t)(tok0 + at) * D_DIM + akq;

    const float* bptr[4];
    int bwr[4];
    #pragma unroll
    for (int q = 0; q < 4; ++q) {
        int fid = tid + 256 * q;
        int e   = fid >> 3;
        int kq  = (fid & 7) << 2;
        const float* base = (e < E_DIM) ? (Wr + (size_t)e * D_DIM)
                                        : (Wn + (size_t)(e - E_DIM) * D_DIM);
        bptr[q] = base + kq;
        bwr[q]  = kq * 132 + e;
    }

    const int r0 = (tid >> 4) << 1;
    const int c0 = (tid & 15) << 3;

    float acc[2][8];
    #pragma unroll
    for (int i = 0; i < 2; ++i)
        #pragma unroll
        for (int j = 0; j < 8; ++j) acc[i][j] = 0.f;

    for (int k0 = 0; k0 < D_DIM; k0 += BK) {
        __syncthreads();
        float4 av = *(const float4*)(aptr + k0);
        As[(akq + 0) * 34 + at] = av.x;
        As[(akq + 1) * 34 + at] = av.y;
        As[(akq + 2) * 34 + at] = av.z;
        As[(akq + 3) * 34 + at] = av.w;
        #pragma unroll
        for (int q = 0; q < 4; ++q) {
            float4 bv = *(const float4*)(bptr[q] + k0);
            Bs[bwr[q] + 0 * 132] = bv.x;
            Bs[bwr[q] + 1 * 132] = bv.y;
            Bs[bwr[q] + 2 * 132] = bv.z;
            Bs[bwr[q] + 3 * 132] = bv.w;
        }
        __syncthreads();

        #pragma unroll
        for (int kk = 0; kk < BK; ++kk) {
            float2 a  = *(const float2*)&As[kk * 34 + r0];
            float4 b0 = *(const float4*)&Bs[kk * 132 + c0];
            float4 b1 = *(const float4*)&Bs[kk * 132 + c0 + 4];
            float aa[2] = {a.x, a.y};
            float bb[8] = {b0.x, b0.y, b0.z, b0.w, b1.x, b1.y, b1.z, b1.w};
            #pragma unroll
            for (int i = 0; i < 2; ++i)
                #pragma unroll
                for (int j = 0; j < 8; ++j)
                    acc[i][j] = fmaf(aa[i], bb[j], acc[i][j]);
        }
    }

    #pragma unroll
    for (int j = 0; j < 8; ++j) {
        int c = c0 + j;
        float bias = (c < E_DIM) ? br[c] : bn[c - E_DIM];
        zs[(r0 + 0) * NCOL + c] = acc[0][j] + bias;
        zs[(r0 + 1) * NCOL + c] = acc[1][j] + bias;
    }
    __syncthreads();

    {
        int t  = tid >> 3;
        int e0 = (tid & 7) << 3;
        const float* ep = eps + (size_t)(tok0 + t) * E_DIM + e0;
        #pragma unroll
        for (int j = 0; j < 8; ++j) {
            float zr = zs[t * NCOL + e0 + j];
            float zn = zs[t * NCOL + E_DIM + e0 + j];
            float sp = fmaxf(zn, 0.f) + log1pf(expf(-fabsf(zn)));
            ns[t * E_DIM + e0 + j] = zr + ep[j] * sp;
        }
    }
    __syncthreads();

    // top-8 (+9th for gap check) + masked softmax: one wave per 8 tokens
    {
        int wv   = tid >> 6;
        int lane = tid & 63;
        for (int tk = 0; tk < 8; ++tk) {
            int t = wv * 8 + tk;
            float v0 = ns[t * E_DIM + lane];
            float v  = v0;
            float m0 = 0.f, denom = 0.f, prev = 0.f, mingap = INFINITY;
            bool selected = false;
            int rankedIdx = 0;
            #pragma unroll
            for (int k = 0; k < KTOP + 1; ++k) {
                float mv = v; int mi = lane;
                #pragma unroll
                for (int off = 32; off > 0; off >>= 1) {
                    float ov = __shfl_xor(mv, off);
                    int   oi = __shfl_xor(mi, off);
                    if (ov > mv || (ov == mv && oi < mi)) { mv = ov; mi = oi; }
                }
                if (k == 0) m0 = mv; else mingap = fminf(mingap, prev - mv);
                prev = mv;
                if (k < KTOP) {
                    denom += expf(mv - m0);
                    if (lane == mi) { selected = true; v = -INFINITY; }
                    if (lane == k) rankedIdx = mi;
                }
            }
            float p = selected ? expf(v0 - m0) / denom : 0.f;
            size_t tg = (size_t)(tok0 + t);
            out_probs[tg * E_DIM + lane] = p;
            if (lane < KTOP) out_idx[tg * KTOP + lane] = (float)rankedIdx;
            if (mingap < TAU && lane == 0) {
                unsigned int w = atomicAdd(cnt, 1u);
                list[w] = (int)tg;
            }
        }
    }
}

// ---------------- Pass 2: fp64 exact recompute for flagged tokens ----------------
// One wave per token; lane = expert. Each lane owns W_route[lane] and
// W_noise[lane] rows; mh row is a wave-broadcast read.
__global__ __launch_bounds__(256)
void refine_fp64(const float* __restrict__ mh,
                 const float* __restrict__ Wr,
                 const float* __restrict__ br,
                 const float* __restrict__ Wn,
                 const float* __restrict__ bn,
                 const float* __restrict__ eps,
                 float* __restrict__ out_probs,
                 float* __restrict__ out_idx,
                 const unsigned int* __restrict__ cnt,
                 const int* __restrict__ list)
{
    const unsigned int n = *cnt;
    const int lane = threadIdx.x & 63;
    const int wv   = threadIdx.x >> 6;

    for (unsigned int g = blockIdx.x; g * 4 < n; g += gridDim.x) {
        unsigned int li = g * 4 + wv;
        if (li >= n) continue;
        int tok = list[li];

        const float* x  = mh + (size_t)tok * D_DIM;
        const float* wr = Wr + (size_t)lane * D_DIM;
        const float* wn = Wn + (size_t)lane * D_DIM;
        double sr = 0.0, sn = 0.0;
        for (int k = 0; k < D_DIM; k += 4) {
            float4 xv = *(const float4*)(x + k);
            float4 rv = *(const float4*)(wr + k);
            float4 nv = *(const float4*)(wn + k);
            sr += (double)xv.x * (double)rv.x;
            sr += (double)xv.y * (double)rv.y;
            sr += (double)xv.z * (double)rv.z;
            sr += (double)xv.w * (double)rv.w;
            sn += (double)xv.x * (double)nv.x;
            sn += (double)xv.y * (double)nv.y;
            sn += (double)xv.z * (double)nv.z;
            sn += (double)xv.w * (double)nv.w;
        }
        double zr = sr + (double)br[lane];
        double zn = sn + (double)bn[lane];
        double sp = fmax(zn, 0.0) + log1p(exp(-fabs(zn)));
        double nl = zr + (double)eps[(size_t)tok * E_DIM + lane] * sp;

        double v = nl, m0 = 0.0, denom = 0.0;
        bool selected = false;
        int rankedIdx = 0;
        #pragma unroll
        for (int k = 0; k < KTOP; ++k) {
            double mv = v; int mi = lane;
            #pragma unroll
            for (int off = 32; off > 0; off >>= 1) {
                double ov = __shfl_xor(mv, off);
                int    oi = __shfl_xor(mi, off);
                if (ov > mv || (ov == mv && oi < mi)) { mv = ov; mi = oi; }
            }
            if (k == 0) m0 = mv;
            denom += exp(mv - m0);
            if (lane == mi) { selected = true; v = -INFINITY; }
            if (lane == k) rankedIdx = mi;
        }
        float p = selected ? (float)(exp(nl - m0) / denom) : 0.f;
        out_probs[(size_t)tok * E_DIM + lane] = p;
        if (lane < KTOP) out_idx[(size_t)tok * KTOP + lane] = (float)rankedIdx;
    }
}

extern "C" void kernel_launch(void* const* d_in, const int* in_sizes, int n_in,
                              void* d_out, int out_size, void* d_ws, size_t ws_size,
                              hipStream_t stream) {
    const float* mh  = (const float*)d_in[0];
    const float* Wr  = (const float*)d_in[1];
    const float* br  = (const float*)d_in[2];
    const float* Wn  = (const float*)d_in[3];
    const float* bn  = (const float*)d_in[4];
    const float* eps = (const float*)d_in[5];

    const int ntok = in_sizes[0] / D_DIM;   // 16384
    float* out_probs = (float*)d_out;                        // [ntok][64]
    float* out_idx   = (float*)d_out + (size_t)ntok * E_DIM; // [ntok][8] as float

    unsigned int* cnt = (unsigned int*)d_ws;
    int* list = (int*)((char*)d_ws + 16);

    hipLaunchKernelGGL(zero_cnt, dim3(1), dim3(1), 0, stream, cnt);
    hipLaunchKernelGGL(noisy_topk_router, dim3(ntok / TPB), dim3(256), 0, stream,
                       mh, Wr, br, Wn, bn, eps, out_probs, out_idx, cnt, list);
    hipLaunchKernelGGL(refine_fp64, dim3(512), dim3(256), 0, stream,
                       mh, Wr, br, Wn, bn, eps, out_probs, out_idx, cnt, list);
}

// Round 5
// 789.764 us; speedup vs baseline: 1.0126x; 1.0100x over previous
//
#include <hip/hip_runtime.h>
#include <math.h>

#define D_DIM 4096
#define E_DIM 64
#define NCOL 128      // route(64) + noise(64) output columns
#define BK 32
#define TPB 32        // tokens per block
#define KTOP 8
#define TAU 1e-3f     // ambiguity threshold: >> worst-case fp32 accum error (1.6e-4)

__global__ void zero_cnt(unsigned int* c) { *c = 0u; }

// ---------------- Pass 1: fp32 GEMM + epilogue + flagging ----------------
// As: [BK][32 tokens] padded stride 34; Bs: [BK][128 cols] padded stride 132
__global__ __launch_bounds__(256, 2)
void noisy_topk_router(const float* __restrict__ mh,
                       const float* __restrict__ Wr,
                       const float* __restrict__ br,
                       const float* __restrict__ Wn,
                       const float* __restrict__ bn,
                       const float* __restrict__ eps,
                       float* __restrict__ out_probs,
                       float* __restrict__ out_idx,
                       unsigned int* __restrict__ cnt,
                       int* __restrict__ list)
{
    __shared__ float As[BK * 34];
    __shared__ float Bs[BK * 132];
    __shared__ float zs[TPB * NCOL];
    __shared__ float ns[TPB * E_DIM];

    const int tid  = threadIdx.x;
    const int tok0 = blockIdx.x * TPB;

    const int at  = tid >> 3;          // 0..31
    const int akq = (tid & 7) << 2;    // 0,4,...,28
    const float* aptr = mh + (size_t)(tok0 + at) * D_DIM + akq;

    const float* bptr[4];
    int bwr[4];
    #pragma unroll
    for (int q = 0; q < 4; ++q) {
        int fid = tid + 256 * q;
        int e   = fid >> 3;
        int kq  = (fid & 7) << 2;
        const float* base = (e < E_DIM) ? (Wr + (size_t)e * D_DIM)
                                        : (Wn + (size_t)(e - E_DIM) * D_DIM);
        bptr[q] = base + kq;
        bwr[q]  = kq * 132 + e;
    }

    const int r0 = (tid >> 4) << 1;
    const int c0 = (tid & 15) << 3;

    float acc[2][8];
    #pragma unroll
    for (int i = 0; i < 2; ++i)
        #pragma unroll
        for (int j = 0; j < 8; ++j) acc[i][j] = 0.f;

    for (int k0 = 0; k0 < D_DIM; k0 += BK) {
        __syncthreads();
        float4 av = *(const float4*)(aptr + k0);
        As[(akq + 0) * 34 + at] = av.x;
        As[(akq + 1) * 34 + at] = av.y;
        As[(akq + 2) * 34 + at] = av.z;
        As[(akq + 3) * 34 + at] = av.w;
        #pragma unroll
        for (int q = 0; q < 4; ++q) {
            float4 bv = *(const float4*)(bptr[q] + k0);
            Bs[bwr[q] + 0 * 132] = bv.x;
            Bs[bwr[q] + 1 * 132] = bv.y;
            Bs[bwr[q] + 2 * 132] = bv.z;
            Bs[bwr[q] + 3 * 132] = bv.w;
        }
        __syncthreads();

        #pragma unroll
        for (int kk = 0; kk < BK; ++kk) {
            float2 a  = *(const float2*)&As[kk * 34 + r0];
            float4 b0 = *(const float4*)&Bs[kk * 132 + c0];
            float4 b1 = *(const float4*)&Bs[kk * 132 + c0 + 4];
            float aa[2] = {a.x, a.y};
            float bb[8] = {b0.x, b0.y, b0.z, b0.w, b1.x, b1.y, b1.z, b1.w};
            #pragma unroll
            for (int i = 0; i < 2; ++i)
                #pragma unroll
                for (int j = 0; j < 8; ++j)
                    acc[i][j] = fmaf(aa[i], bb[j], acc[i][j]);
        }
    }

    #pragma unroll
    for (int j = 0; j < 8; ++j) {
        int c = c0 + j;
        float bias = (c < E_DIM) ? br[c] : bn[c - E_DIM];
        zs[(r0 + 0) * NCOL + c] = acc[0][j] + bias;
        zs[(r0 + 1) * NCOL + c] = acc[1][j] + bias;
    }
    __syncthreads();

    {
        int t  = tid >> 3;
        int e0 = (tid & 7) << 3;
        const float* ep = eps + (size_t)(tok0 + t) * E_DIM + e0;
        #pragma unroll
        for (int j = 0; j < 8; ++j) {
            float zr = zs[t * NCOL + e0 + j];
            float zn = zs[t * NCOL + E_DIM + e0 + j];
            float sp = fmaxf(zn, 0.f) + log1pf(expf(-fabsf(zn)));
            ns[t * E_DIM + e0 + j] = zr + ep[j] * sp;
        }
    }
    __syncthreads();

    // top-8 (+9th for gap check) + masked softmax: one wave per 8 tokens
    {
        int wv   = tid >> 6;
        int lane = tid & 63;
        for (int tk = 0; tk < 8; ++tk) {
            int t = wv * 8 + tk;
            float v0 = ns[t * E_DIM + lane];
            float v  = v0;
            float m0 = 0.f, denom = 0.f, prev = 0.f, mingap = INFINITY;
            bool selected = false;
            int rankedIdx = 0;
            #pragma unroll
            for (int k = 0; k < KTOP + 1; ++k) {
                float mv = v; int mi = lane;
                #pragma unroll
                for (int off = 32; off > 0; off >>= 1) {
                    float ov = __shfl_xor(mv, off);
                    int   oi = __shfl_xor(mi, off);
                    if (ov > mv || (ov == mv && oi < mi)) { mv = ov; mi = oi; }
                }
                if (k == 0) m0 = mv; else mingap = fminf(mingap, prev - mv);
                prev = mv;
                if (k < KTOP) {
                    denom += expf(mv - m0);
                    if (lane == mi) { selected = true; v = -INFINITY; }
                    if (lane == k) rankedIdx = mi;
                }
            }
            float p = selected ? expf(v0 - m0) / denom : 0.f;
            size_t tg = (size_t)(tok0 + t);
            out_probs[tg * E_DIM + lane] = p;
            if (lane < KTOP) out_idx[tg * KTOP + lane] = (float)rankedIdx;
            if (mingap < TAU && lane == 0) {
                unsigned int w = atomicAdd(cnt, 1u);
                list[w] = (int)tg;
            }
        }
    }
}

// ---------------- Pass 2: fp64 exact recompute for flagged tokens ----------------
// One wave per token; lane = expert. Each lane owns W_route[lane] and
// W_noise[lane] rows; mh row is a wave-broadcast read.
__global__ __launch_bounds__(256)
void refine_fp64(const float* __restrict__ mh,
                 const float* __restrict__ Wr,
                 const float* __restrict__ br,
                 const float* __restrict__ Wn,
                 const float* __restrict__ bn,
                 const float* __restrict__ eps,
                 float* __restrict__ out_probs,
                 float* __restrict__ out_idx,
                 const unsigned int* __restrict__ cnt,
                 const int* __restrict__ list)
{
    const unsigned int n = *cnt;
    const int lane = threadIdx.x & 63;
    const int wv   = threadIdx.x >> 6;

    for (unsigned int g = blockIdx.x; g * 4 < n; g += gridDim.x) {
        unsigned int li = g * 4 + wv;
        if (li >= n) continue;
        int tok = list[li];

        const float* x  = mh + (size_t)tok * D_DIM;
        const float* wr = Wr + (size_t)lane * D_DIM;
        const float* wn = Wn + (size_t)lane * D_DIM;
        double sr = 0.0, sn = 0.0;
        for (int k = 0; k < D_DIM; k += 4) {
            float4 xv = *(const float4*)(x + k);
            float4 rv = *(const float4*)(wr + k);
            float4 nv = *(const float4*)(wn + k);
            sr += (double)xv.x * (double)rv.x;
            sr += (double)xv.y * (double)rv.y;
            sr += (double)xv.z * (double)rv.z;
            sr += (double)xv.w * (double)rv.w;
            sn += (double)xv.x * (double)nv.x;
            sn += (double)xv.y * (double)nv.y;
            sn += (double)xv.z * (double)nv.z;
            sn += (double)xv.w * (double)nv.w;
        }
        double zr = sr + (double)br[lane];
        double zn = sn + (double)bn[lane];
        double sp = fmax(zn, 0.0) + log1p(exp(-fabs(zn)));
        double nl = zr + (double)eps[(size_t)tok * E_DIM + lane] * sp;

        double v = nl, m0 = 0.0, denom = 0.0;
        bool selected = false;
        int rankedIdx = 0;
        #pragma unroll
        for (int k = 0; k < KTOP; ++k) {
            double mv = v; int mi = lane;
            #pragma unroll
            for (int off = 32; off > 0; off >>= 1) {
                double ov = __shfl_xor(mv, off);
                int    oi = __shfl_xor(mi, off);
                if (ov > mv || (ov == mv && oi < mi)) { mv = ov; mi = oi; }
            }
            if (k == 0) m0 = mv;
            denom += exp(mv - m0);
            if (lane == mi) { selected = true; v = -INFINITY; }
            if (lane == k) rankedIdx = mi;
        }
        float p = selected ? (float)(exp(nl - m0) / denom) : 0.f;
        out_probs[(size_t)tok * E_DIM + lane] = p;
        if (lane < KTOP) out_idx[(size_t)tok * KTOP + lane] = (float)rankedIdx;
    }
}

extern "C" void kernel_launch(void* const* d_in, const int* in_sizes, int n_in,
                              void* d_out, int out_size, void* d_ws, size_t ws_size,
                              hipStream_t stream) {
    const float* mh  = (const float*)d_in[0];
    const float* Wr  = (const float*)d_in[1];
    const float* br  = (const float*)d_in[2];
    const float* Wn  = (const float*)d_in[3];
    const float* bn  = (const float*)d_in[4];
    const float* eps = (const float*)d_in[5];

    const int ntok = in_sizes[0] / D_DIM;   // 16384
    float* out_probs = (float*)d_out;                        // [ntok][64]
    float* out_idx   = (float*)d_out + (size_t)ntok * E_DIM; // [ntok][8] as float

    unsigned int* cnt = (unsigned int*)d_ws;
    int* list = (int*)((char*)d_ws + 16);

    hipLaunchKernelGGL(zero_cnt, dim3(1), dim3(1), 0, stream, cnt);
    hipLaunchKernelGGL(noisy_topk_router, dim3(ntok / TPB), dim3(256), 0, stream,
                       mh, Wr, br, Wn, bn, eps, out_probs, out_idx, cnt, list);
    hipLaunchKernelGGL(refine_fp64, dim3(512), dim3(256), 0, stream,
                       mh, Wr, br, Wn, bn, eps, out_probs, out_idx, cnt, list);
}

// Round 6
// 479.892 us; speedup vs baseline: 1.6665x; 1.6457x over previous
//
#include <hip/hip_runtime.h>
#include <math.h>

#define D_DIM 4096
#define E_DIM 64
#define KTOP 8
#define TAU 1e-3f     // ambiguity threshold: >> split-bf16 GEMM error (~1e-5)
#define BM 64         // tokens per block (main)
#define BKT 32        // k per tile
#define NT (D_DIM / BKT)   // 128 tiles

// workspace layout (bytes)
#define WS_CNT 0
#define WS_LIST 1024
#define WS_IMG 66560  // 1024 + 64KB list; 16B aligned

typedef __attribute__((ext_vector_type(8))) short bf16x8;
typedef __attribute__((ext_vector_type(4))) float f32x4;

#define MFMA(a, b, c) __builtin_amdgcn_mfma_f32_16x16x32_bf16(a, b, c, 0, 0, 0)

__global__ void zero_cnt(unsigned int* c) { *c = 0u; }

__device__ inline unsigned short bf16_rne(float x) {
    unsigned int b = __float_as_uint(x);
    return (unsigned short)((b + 0x7FFFu + ((b >> 16) & 1u)) >> 16);
}

// ---- preconvert weights: Wr||Wn -> hi/lo bf16 image, fragment-linear per k-tile ----
// image (ushort idx): tile kt: hi at kt*8192 + koff*1024 + col*8 + j ; lo at +4096
__global__ __launch_bounds__(256)
void preconv(const float* __restrict__ Wr, const float* __restrict__ Wn,
             unsigned short* __restrict__ img)
{
    int t = blockIdx.x * 256 + threadIdx.x;      // 0..524287
    int kt = t >> 12, rem = t & 4095;
    int koff = rem >> 10, colj = rem & 1023;
    int col = colj >> 3, j = colj & 7;
    int k = kt * 32 + koff * 8 + j;
    float x = (col < E_DIM) ? Wr[(size_t)col * D_DIM + k]
                            : Wn[(size_t)(col - E_DIM) * D_DIM + k];
    unsigned short h = bf16_rne(x);
    float hf = __uint_as_float((unsigned int)h << 16);
    float r = x - hf;                             // exact (Sterbenz)
    unsigned short l = bf16_rne(r);
    img[(size_t)kt * 8192 + koff * 1024 + colj] = h;
    img[(size_t)kt * 8192 + 4096 + koff * 1024 + colj] = l;
}

// ---- split 8 fp32 -> hi/lo bf16x8 via v_cvt_pk_bf16_f32 (RNE) ----
__device__ inline void split8(float4 p, float4 q, bf16x8& h8, bf16x8& l8) {
    float xx[8] = {p.x, p.y, p.z, p.w, q.x, q.y, q.z, q.w};
    union { unsigned int w[4]; bf16x8 v; } H, L;
    #pragma unroll
    for (int i = 0; i < 4; ++i) {
        float a = xx[2 * i], b = xx[2 * i + 1];
        unsigned int hw;
        asm("v_cvt_pk_bf16_f32 %0, %1, %2" : "=v"(hw) : "v"(a), "v"(b));
        float ha = __uint_as_float(hw << 16);
        float hb = __uint_as_float(hw & 0xFFFF0000u);
        float ra = a - ha, rb = b - hb;           // exact residuals
        unsigned int lw;
        asm("v_cvt_pk_bf16_f32 %0, %1, %2" : "=v"(lw) : "v"(ra), "v"(rb));
        H.w[i] = hw; L.w[i] = lw;
    }
    h8 = H.v; l8 = L.v;
}

// ---- main: split-bf16 MFMA GEMM + epilogue + flagging ----
__global__ __launch_bounds__(512, 2)
void router_main(const float* __restrict__ mh,
                 const unsigned short* __restrict__ Wimg,
                 const float* __restrict__ br, const float* __restrict__ bn,
                 const float* __restrict__ eps,
                 float* __restrict__ out_probs, float* __restrict__ out_idx,
                 unsigned int* __restrict__ cnt, int* __restrict__ list)
{
    extern __shared__ char smem[];
    unsigned short* Bb = (unsigned short*)smem;   // [2][8192] ushorts (32KB), GEMM phase
    float* zs = (float*)smem;                     // [64][132] overlay, epilogue
    float* ns = (float*)(smem + 33792);           // [64][68]

    const int tid  = threadIdx.x;
    const int lane = tid & 63;
    const int wv   = tid >> 6;       // 0..7
    const int wr   = wv >> 1;        // rowgroup 0..3 (16 tokens each)
    const int wc   = wv & 1;         // colgroup 0..1 (64 cols each)
    const int tok0 = blockIdx.x * BM;
    const int rloc = lane & 15;
    const int koff = lane >> 4;      // 0..3

    const float* aptr = mh + (size_t)(tok0 + wr * 16 + rloc) * D_DIM + koff * 8;

    int boff[4];
    #pragma unroll
    for (int fc = 0; fc < 4; ++fc)
        boff[fc] = koff * 1024 + (wc * 64 + fc * 16 + rloc) * 8;

    const int4* gimg = (const int4*)Wimg;   // 1024 int4 per k-tile
    int4* Bb4 = (int4*)Bb;                  // 1024 int4 per buffer

    // prologue: stage tile 0
    int4 s0 = gimg[tid], s1 = gimg[512 + tid];
    Bb4[tid] = s0; Bb4[512 + tid] = s1;

    f32x4 acc[4];
    #pragma unroll
    for (int fc = 0; fc < 4; ++fc) acc[fc] = {0.f, 0.f, 0.f, 0.f};

    for (int kt = 0; kt < NT; ++kt) {
        const int cb = kt & 1;
        if (kt + 1 < NT) {                       // issue next-tile loads early (T14)
            s0 = gimg[(size_t)(kt + 1) * 1024 + tid];
            s1 = gimg[(size_t)(kt + 1) * 1024 + 512 + tid];
        }
        __syncthreads();                         // tile kt's ds_writes visible

        float4 a0 = *(const float4*)(aptr + kt * BKT);
        float4 a1 = *(const float4*)(aptr + kt * BKT + 4);
        bf16x8 ah, al;
        split8(a0, a1, ah, al);

        const unsigned short* bb = Bb + cb * 8192;
        bf16x8 bh[4], bl[4];
        #pragma unroll
        for (int fc = 0; fc < 4; ++fc) {
            bh[fc] = *(const bf16x8*)(bb + boff[fc]);
            bl[fc] = *(const bf16x8*)(bb + 4096 + boff[fc]);
        }
        #pragma unroll
        for (int fc = 0; fc < 4; ++fc) {
            acc[fc] = MFMA(ah, bh[fc], acc[fc]);
            acc[fc] = MFMA(al, bh[fc], acc[fc]);
            acc[fc] = MFMA(ah, bl[fc], acc[fc]);
        }
        if (kt + 1 < NT) {                       // write next tile (buf read last in kt-1)
            const int nb = cb ^ 1;
            Bb4[nb * 1024 + tid] = s0;
            Bb4[nb * 1024 + 512 + tid] = s1;
        }
    }
    __syncthreads();   // all ds_reads done before zs overlays Bb

    // acc -> zs (+bias). C-layout: col=lane&15, row=(lane>>4)*4+reg (m89-verified)
    #pragma unroll
    for (int fc = 0; fc < 4; ++fc) {
        const int col = wc * 64 + fc * 16 + rloc;
        const float bias = (col < E_DIM) ? br[col] : bn[col - E_DIM];
        #pragma unroll
        for (int rg = 0; rg < 4; ++rg) {
            const int row = wr * 16 + koff * 4 + rg;
            zs[row * 132 + col] = acc[fc][rg] + bias;
        }
    }
    __syncthreads();

    // noisy logits
    {
        const int t  = tid >> 3;                 // 0..63
        const int e0 = (tid & 7) << 3;
        const float* ep = eps + (size_t)(tok0 + t) * E_DIM + e0;
        #pragma unroll
        for (int j = 0; j < 8; ++j) {
            float zr = zs[t * 132 + e0 + j];
            float zn = zs[t * 132 + 64 + e0 + j];
            float sp = fmaxf(zn, 0.f) + log1pf(expf(-fabsf(zn)));
            ns[t * 68 + e0 + j] = zr + ep[j] * sp;
        }
    }
    __syncthreads();

    // top-8 (+9th for gap) + masked softmax: wave wv handles tokens wv*8..wv*8+7
    for (int tk = 0; tk < 8; ++tk) {
        int t = wv * 8 + tk;
        float v0 = ns[t * 68 + lane];
        float v  = v0;
        float m0 = 0.f, denom = 0.f, prev = 0.f, mingap = INFINITY;
        bool selected = false;
        int rankedIdx = 0;
        #pragma unroll
        for (int k = 0; k < KTOP + 1; ++k) {
            float mv = v; int mi = lane;
            #pragma unroll
            for (int off = 32; off > 0; off >>= 1) {
                float ov = __shfl_xor(mv, off);
                int   oi = __shfl_xor(mi, off);
                if (ov > mv || (ov == mv && oi < mi)) { mv = ov; mi = oi; }
            }
            if (k == 0) m0 = mv; else mingap = fminf(mingap, prev - mv);
            prev = mv;
            if (k < KTOP) {
                denom += expf(mv - m0);
                if (lane == mi) { selected = true; v = -INFINITY; }
                if (lane == k) rankedIdx = mi;
            }
        }
        float p = selected ? expf(v0 - m0) / denom : 0.f;
        size_t tg = (size_t)(tok0 + t);
        out_probs[tg * E_DIM + lane] = p;
        if (lane < KTOP) out_idx[tg * KTOP + lane] = (float)rankedIdx;
        if (mingap < TAU && lane == 0) {
            unsigned int wpos = atomicAdd(cnt, 1u);
            list[wpos] = (int)tg;
        }
    }
}

// ---- fp64 exact recompute for flagged tokens: 1 block/token, 4 waves split K ----
__global__ __launch_bounds__(256)
void refine_fp64(const float* __restrict__ mh,
                 const float* __restrict__ Wr, const float* __restrict__ br,
                 const float* __restrict__ Wn, const float* __restrict__ bn,
                 const float* __restrict__ eps,
                 float* __restrict__ out_probs, float* __restrict__ out_idx,
                 const unsigned int* __restrict__ cnt, const int* __restrict__ list)
{
    __shared__ double red[8][64];
    const unsigned int n = *cnt;
    const int lane = threadIdx.x & 63;   // expert
    const int w    = threadIdx.x >> 6;   // k-quarter

    for (unsigned int i = blockIdx.x; i < n; i += gridDim.x) {
        const int tok = list[i];
        const float* x  = mh + (size_t)tok * D_DIM + w * 1024;
        const float* wrp = Wr + (size_t)lane * D_DIM + w * 1024;
        const float* wnp = Wn + (size_t)lane * D_DIM + w * 1024;
        double sr = 0.0, sn = 0.0;
        for (int k = 0; k < 1024; k += 4) {
            float4 xv = *(const float4*)(x + k);
            float4 rv = *(const float4*)(wrp + k);
            float4 nv = *(const float4*)(wnp + k);
            sr += (double)xv.x * rv.x; sr += (double)xv.y * rv.y;
            sr += (double)xv.z * rv.z; sr += (double)xv.w * rv.w;
            sn += (double)xv.x * nv.x; sn += (double)xv.y * nv.y;
            sn += (double)xv.z * nv.z; sn += (double)xv.w * nv.w;
        }
        red[w * 2][lane] = sr; red[w * 2 + 1][lane] = sn;
        __syncthreads();
        if (w == 0) {
            double zr = ((red[0][lane] + red[2][lane]) + (red[4][lane] + red[6][lane]))
                        + (double)br[lane];
            double zn = ((red[1][lane] + red[3][lane]) + (red[5][lane] + red[7][lane]))
                        + (double)bn[lane];
            double sp = fmax(zn, 0.0) + log1p(exp(-fabs(zn)));
            double nl = zr + (double)eps[(size_t)tok * E_DIM + lane] * sp;
            double v = nl, m0 = 0.0, denom = 0.0;
            bool selected = false;
            int rankedIdx = 0;
            #pragma unroll
            for (int k = 0; k < KTOP; ++k) {
                double mv = v; int mi = lane;
                #pragma unroll
                for (int off = 32; off > 0; off >>= 1) {
                    double ov = __shfl_xor(mv, off);
                    int    oi = __shfl_xor(mi, off);
                    if (ov > mv || (ov == mv && oi < mi)) { mv = ov; mi = oi; }
                }
                if (k == 0) m0 = mv;
                denom += exp(mv - m0);
                if (lane == mi) { selected = true; v = -INFINITY; }
                if (lane == k) rankedIdx = mi;
            }
            float p = selected ? (float)(exp(nl - m0) / denom) : 0.f;
            out_probs[(size_t)tok * E_DIM + lane] = p;
            if (lane < KTOP) out_idx[(size_t)tok * KTOP + lane] = (float)rankedIdx;
        }
        __syncthreads();
    }
}

extern "C" void kernel_launch(void* const* d_in, const int* in_sizes, int n_in,
                              void* d_out, int out_size, void* d_ws, size_t ws_size,
                              hipStream_t stream) {
    const float* mh  = (const float*)d_in[0];
    const float* Wr  = (const float*)d_in[1];
    const float* br  = (const float*)d_in[2];
    const float* Wn  = (const float*)d_in[3];
    const float* bn  = (const float*)d_in[4];
    const float* eps = (const float*)d_in[5];

    const int ntok = in_sizes[0] / D_DIM;                     // 16384
    float* out_probs = (float*)d_out;                         // [ntok][64]
    float* out_idx   = (float*)d_out + (size_t)ntok * E_DIM;  // [ntok][8] as float

    unsigned int* cnt = (unsigned int*)d_ws;
    int* list = (int*)((char*)d_ws + WS_LIST);
    unsigned short* img = (unsigned short*)((char*)d_ws + WS_IMG);

    hipLaunchKernelGGL(zero_cnt, dim3(1), dim3(1), 0, stream, cnt);
    hipLaunchKernelGGL(preconv, dim3(2048), dim3(256), 0, stream, Wr, Wn, img);
    hipLaunchKernelGGL(router_main, dim3(ntok / BM), dim3(512), 51200, stream,
                       mh, img, br, bn, eps, out_probs, out_idx, cnt, list);
    hipLaunchKernelGGL(refine_fp64, dim3(2048), dim3(256), 0, stream,
                       mh, Wr, br, Wn, bn, eps, out_probs, out_idx, cnt, list);
}

// Round 7
// 348.381 us; speedup vs baseline: 2.2956x; 1.3775x over previous
//
#include <hip/hip_runtime.h>
#include <math.h>

#define D_DIM 4096
#define E_DIM 64
#define KTOP 8
#define TAU 2e-4f     // ambiguity threshold: ~66 sigma of split-bf16 GEMM error (~3e-6 RMS)
#define BM 64         // tokens per block (main)
#define BKT 32        // k per tile
#define NT (D_DIM / BKT)   // 128 tiles

// workspace layout (bytes)
#define WS_CNT 0
#define WS_LIST 1024
#define WS_IMG 66560  // 1024 + 64KB list (room for ALL tokens); 16B aligned

typedef __attribute__((ext_vector_type(8))) short bf16x8;
typedef __attribute__((ext_vector_type(4))) float f32x4;

#define MFMA(a, b, c) __builtin_amdgcn_mfma_f32_16x16x32_bf16(a, b, c, 0, 0, 0)

__global__ void zero_cnt(unsigned int* c) { *c = 0u; }

__device__ inline unsigned short bf16_rne(float x) {
    unsigned int b = __float_as_uint(x);
    return (unsigned short)((b + 0x7FFFu + ((b >> 16) & 1u)) >> 16);
}

// ---- preconvert weights: Wr||Wn -> hi/lo bf16 image, fragment-linear per k-tile ----
// image (ushort idx): tile kt: hi at kt*8192 + koff*1024 + col*8 + j ; lo at +4096
__global__ __launch_bounds__(256)
void preconv(const float* __restrict__ Wr, const float* __restrict__ Wn,
             unsigned short* __restrict__ img)
{
    int t = blockIdx.x * 256 + threadIdx.x;      // 0..524287
    int kt = t >> 12, rem = t & 4095;
    int koff = rem >> 10, colj = rem & 1023;
    int col = colj >> 3, j = colj & 7;
    int k = kt * 32 + koff * 8 + j;
    float x = (col < E_DIM) ? Wr[(size_t)col * D_DIM + k]
                            : Wn[(size_t)(col - E_DIM) * D_DIM + k];
    unsigned short h = bf16_rne(x);
    float hf = __uint_as_float((unsigned int)h << 16);
    float r = x - hf;                             // exact (Sterbenz)
    unsigned short l = bf16_rne(r);
    img[(size_t)kt * 8192 + koff * 1024 + colj] = h;
    img[(size_t)kt * 8192 + 4096 + koff * 1024 + colj] = l;
}

// ---- split 8 fp32 -> hi/lo bf16x8 via v_cvt_pk_bf16_f32 (RNE) ----
__device__ inline void split8(float4 p, float4 q, bf16x8& h8, bf16x8& l8) {
    float xx[8] = {p.x, p.y, p.z, p.w, q.x, q.y, q.z, q.w};
    union { unsigned int w[4]; bf16x8 v; } H, L;
    #pragma unroll
    for (int i = 0; i < 4; ++i) {
        float a = xx[2 * i], b = xx[2 * i + 1];
        unsigned int hw;
        asm("v_cvt_pk_bf16_f32 %0, %1, %2" : "=v"(hw) : "v"(a), "v"(b));
        float ha = __uint_as_float(hw << 16);
        float hb = __uint_as_float(hw & 0xFFFF0000u);
        float ra = a - ha, rb = b - hb;           // exact residuals
        unsigned int lw;
        asm("v_cvt_pk_bf16_f32 %0, %1, %2" : "=v"(lw) : "v"(ra), "v"(rb));
        H.w[i] = hw; L.w[i] = lw;
    }
    h8 = H.v; l8 = L.v;
}

// ---- main: split-bf16 MFMA GEMM + epilogue + flagging ----
__global__ __launch_bounds__(512, 2)
void router_main(const float* __restrict__ mh,
                 const unsigned short* __restrict__ Wimg,
                 const float* __restrict__ br, const float* __restrict__ bn,
                 const float* __restrict__ eps,
                 float* __restrict__ out_probs, float* __restrict__ out_idx,
                 unsigned int* __restrict__ cnt, int* __restrict__ list)
{
    extern __shared__ char smem[];
    unsigned short* Bb = (unsigned short*)smem;   // [2][8192] ushorts (32KB), GEMM phase
    float* zs = (float*)smem;                     // [64][132] overlay, epilogue
    float* ns = (float*)(smem + 33792);           // [64][68]

    const int tid  = threadIdx.x;
    const int lane = tid & 63;
    const int wv   = tid >> 6;       // 0..7
    const int wr   = wv >> 1;        // rowgroup 0..3 (16 tokens each)
    const int wc   = wv & 1;         // colgroup 0..1 (64 cols each)
    const int tok0 = blockIdx.x * BM;
    const int rloc = lane & 15;
    const int koff = lane >> 4;      // 0..3

    const float* aptr = mh + (size_t)(tok0 + wr * 16 + rloc) * D_DIM + koff * 8;

    int boff[4];
    #pragma unroll
    for (int fc = 0; fc < 4; ++fc)
        boff[fc] = koff * 1024 + (wc * 64 + fc * 16 + rloc) * 8;

    const int4* gimg = (const int4*)Wimg;   // 1024 int4 per k-tile
    int4* Bb4 = (int4*)Bb;                  // 1024 int4 per buffer

    f32x4 acc[4];
    #pragma unroll
    for (int fc = 0; fc < 4; ++fc) acc[fc] = {0.f, 0.f, 0.f, 0.f};

    auto tile_mfma = [&](const unsigned short* bb, bf16x8 ah, bf16x8 al) {
        bf16x8 bh[4], bl[4];
        #pragma unroll
        for (int fc = 0; fc < 4; ++fc) {
            bh[fc] = *(const bf16x8*)(bb + boff[fc]);
            bl[fc] = *(const bf16x8*)(bb + 4096 + boff[fc]);
        }
        #pragma unroll
        for (int fc = 0; fc < 4; ++fc) {
            acc[fc] = MFMA(ah, bh[fc], acc[fc]);
            acc[fc] = MFMA(al, bh[fc], acc[fc]);
            acc[fc] = MFMA(ah, bl[fc], acc[fc]);
        }
    };

    // prologue: stage B tile0 direct; preload B tile1 regs; preload A tiles 0,1
    {
        int4 b0 = gimg[tid], b1 = gimg[512 + tid];
        Bb4[tid] = b0; Bb4[512 + tid] = b1;
    }
    int4 p1a = gimg[1024 + tid],        p1b = gimg[1024 + 512 + tid];  // B tile 1
    int4 p2a, p2b;                                                     // B tile kt+2
    float4 a0A = *(const float4*)(aptr + 0),  a1A = *(const float4*)(aptr + 4);
    float4 a0B = *(const float4*)(aptr + 32), a1B = *(const float4*)(aptr + 36);

    for (int kt = 0; kt < NT; kt += 2) {
        // ---- EVEN tile kt: A in a*A, B in Bb[0] ----
        if (kt + 2 < NT) {  // issue B(kt+2), consumed end of ODD
            p2a = gimg[(size_t)(kt + 2) * 1024 + tid];
            p2b = gimg[(size_t)(kt + 2) * 1024 + 512 + tid];
        }
        __syncthreads();                          // Bb[0] (tile kt) visible
        {
            bf16x8 ah, al;
            split8(a0A, a1A, ah, al);
            if (kt + 2 < NT) {                    // A 2-deep prefetch
                a0A = *(const float4*)(aptr + (kt + 2) * 32);
                a1A = *(const float4*)(aptr + (kt + 2) * 32 + 4);
            }
            tile_mfma(Bb, ah, al);
        }
        if (kt + 1 < NT) {                        // write B(kt+1) -> Bb[1]
            Bb4[1024 + tid] = p1a; Bb4[1024 + 512 + tid] = p1b;
        }

        // ---- ODD tile kt+1: A in a*B, B in Bb[1] ----
        if (kt + 3 < NT) {  // issue B(kt+3), consumed end of next EVEN
            p1a = gimg[(size_t)(kt + 3) * 1024 + tid];
            p1b = gimg[(size_t)(kt + 3) * 1024 + 512 + tid];
        }
        __syncthreads();                          // Bb[1] (tile kt+1) visible
        {
            bf16x8 ah, al;
            split8(a0B, a1B, ah, al);
            if (kt + 3 < NT) {
                a0B = *(const float4*)(aptr + (kt + 3) * 32);
                a1B = *(const float4*)(aptr + (kt + 3) * 32 + 4);
            }
            tile_mfma(Bb + 8192, ah, al);
        }
        if (kt + 2 < NT) {                        // write B(kt+2) -> Bb[0]
            Bb4[tid] = p2a; Bb4[512 + tid] = p2b;
        }
    }
    __syncthreads();   // all ds_reads done before zs overlays Bb

    // acc -> zs (+bias). C-layout: col=lane&15, row=(lane>>4)*4+reg (m89-verified)
    #pragma unroll
    for (int fc = 0; fc < 4; ++fc) {
        const int col = wc * 64 + fc * 16 + rloc;
        const float bias = (col < E_DIM) ? br[col] : bn[col - E_DIM];
        #pragma unroll
        for (int rg = 0; rg < 4; ++rg) {
            const int row = wr * 16 + koff * 4 + rg;
            zs[row * 132 + col] = acc[fc][rg] + bias;
        }
    }
    __syncthreads();

    // noisy logits
    {
        const int t  = tid >> 3;                 // 0..63
        const int e0 = (tid & 7) << 3;
        const float* ep = eps + (size_t)(tok0 + t) * E_DIM + e0;
        #pragma unroll
        for (int j = 0; j < 8; ++j) {
            float zr = zs[t * 132 + e0 + j];
            float zn = zs[t * 132 + 64 + e0 + j];
            float sp = fmaxf(zn, 0.f) + log1pf(expf(-fabsf(zn)));
            ns[t * 68 + e0 + j] = zr + ep[j] * sp;
        }
    }
    __syncthreads();

    // top-8 (+9th for gap) + masked softmax: wave wv handles tokens wv*8..wv*8+7
    for (int tk = 0; tk < 8; ++tk) {
        int t = wv * 8 + tk;
        float v0 = ns[t * 68 + lane];
        float v  = v0;
        float m0 = 0.f, denom = 0.f, prev = 0.f, mingap = INFINITY;
        bool selected = false;
        int rankedIdx = 0;
        #pragma unroll
        for (int k = 0; k < KTOP + 1; ++k) {
            float mv = v; int mi = lane;
            #pragma unroll
            for (int off = 32; off > 0; off >>= 1) {
                float ov = __shfl_xor(mv, off);
                int   oi = __shfl_xor(mi, off);
                if (ov > mv || (ov == mv && oi < mi)) { mv = ov; mi = oi; }
            }
            if (k == 0) m0 = mv; else mingap = fminf(mingap, prev - mv);
            prev = mv;
            if (k < KTOP) {
                denom += expf(mv - m0);
                if (lane == mi) { selected = true; v = -INFINITY; }
                if (lane == k) rankedIdx = mi;
            }
        }
        float p = selected ? expf(v0 - m0) / denom : 0.f;
        size_t tg = (size_t)(tok0 + t);
        out_probs[tg * E_DIM + lane] = p;
        if (lane < KTOP) out_idx[tg * KTOP + lane] = (float)rankedIdx;
        if (mingap < TAU && lane == 0) {
            unsigned int wpos = atomicAdd(cnt, 1u);
            list[wpos] = (int)tg;
        }
    }
}

// ---- fp64 exact recompute for flagged tokens: 1 block/token ----
// x-row staged in LDS (fp64); each wave owns 32 of the 128 W-rows; lanes split
// k (coalesced float4 loads); 4 independent fp64 chains; butterfly reduce.
__global__ __launch_bounds__(256)
void refine_fp64(const float* __restrict__ mh,
                 const float* __restrict__ Wr, const float* __restrict__ br,
                 const float* __restrict__ Wn, const float* __restrict__ bn,
                 const float* __restrict__ eps,
                 float* __restrict__ out_probs, float* __restrict__ out_idx,
                 const unsigned int* __restrict__ cnt, const int* __restrict__ list)
{
    __shared__ double xs[D_DIM];   // 32KB
    __shared__ double red[128];
    const unsigned int n = *cnt;
    const int tid  = threadIdx.x;
    const int lane = tid & 63;
    const int wv   = tid >> 6;     // 0..3

    for (unsigned int i = blockIdx.x; i < n; i += gridDim.x) {
        const int tok = list[i];
        // stage x as fp64 (coalesced)
        for (int k = tid * 4; k < D_DIM; k += 1024) {
            float4 xv = *(const float4*)(mh + (size_t)tok * D_DIM + k);
            xs[k]     = (double)xv.x; xs[k + 1] = (double)xv.y;
            xs[k + 2] = (double)xv.z; xs[k + 3] = (double)xv.w;
        }
        __syncthreads();

        for (int r = 0; r < 32; ++r) {
            const int row = wv * 32 + r;
            const float* wp = (row < E_DIM) ? (Wr + (size_t)row * D_DIM)
                                            : (Wn + (size_t)(row - E_DIM) * D_DIM);
            double s0 = 0.0, s1 = 0.0, s2 = 0.0, s3 = 0.0;
            #pragma unroll 4
            for (int k = lane * 4; k < D_DIM; k += 256) {
                float4 w4 = *(const float4*)(wp + k);
                s0 += xs[k]     * (double)w4.x;
                s1 += xs[k + 1] * (double)w4.y;
                s2 += xs[k + 2] * (double)w4.z;
                s3 += xs[k + 3] * (double)w4.w;
            }
            double s = (s0 + s1) + (s2 + s3);
            #pragma unroll
            for (int off = 32; off > 0; off >>= 1) s += __shfl_xor(s, off);
            if (lane == 0) red[row] = s;
        }
        __syncthreads();

        if (wv == 0) {   // epilogue: lane = expert
            double zr = red[lane] + (double)br[lane];
            double zn = red[E_DIM + lane] + (double)bn[lane];
            double sp = fmax(zn, 0.0) + log1p(exp(-fabs(zn)));
            double nl = zr + (double)eps[(size_t)tok * E_DIM + lane] * sp;
            double v = nl, m0 = 0.0, denom = 0.0;
            bool selected = false;
            int rankedIdx = 0;
            #pragma unroll
            for (int k = 0; k < KTOP; ++k) {
                double mv = v; int mi = lane;
                #pragma unroll
                for (int off = 32; off > 0; off >>= 1) {
                    double ov = __shfl_xor(mv, off);
                    int    oi = __shfl_xor(mi, off);
                    if (ov > mv || (ov == mv && oi < mi)) { mv = ov; mi = oi; }
                }
                if (k == 0) m0 = mv;
                denom += exp(mv - m0);
                if (lane == mi) { selected = true; v = -INFINITY; }
                if (lane == k) rankedIdx = mi;
            }
            float p = selected ? (float)(exp(nl - m0) / denom) : 0.f;
            out_probs[(size_t)tok * E_DIM + lane] = p;
            if (lane < KTOP) out_idx[(size_t)tok * KTOP + lane] = (float)rankedIdx;
        }
        __syncthreads();   // xs reused next iteration
    }
}

extern "C" void kernel_launch(void* const* d_in, const int* in_sizes, int n_in,
                              void* d_out, int out_size, void* d_ws, size_t ws_size,
                              hipStream_t stream) {
    const float* mh  = (const float*)d_in[0];
    const float* Wr  = (const float*)d_in[1];
    const float* br  = (const float*)d_in[2];
    const float* Wn  = (const float*)d_in[3];
    const float* bn  = (const float*)d_in[4];
    const float* eps = (const float*)d_in[5];

    const int ntok = in_sizes[0] / D_DIM;                     // 16384
    float* out_probs = (float*)d_out;                         // [ntok][64]
    float* out_idx   = (float*)d_out + (size_t)ntok * E_DIM;  // [ntok][8] as float

    unsigned int* cnt = (unsigned int*)d_ws;
    int* list = (int*)((char*)d_ws + WS_LIST);
    unsigned short* img = (unsigned short*)((char*)d_ws + WS_IMG);

    hipLaunchKernelGGL(zero_cnt, dim3(1), dim3(1), 0, stream, cnt);
    hipLaunchKernelGGL(preconv, dim3(2048), dim3(256), 0, stream, Wr, Wn, img);
    hipLaunchKernelGGL(router_main, dim3(ntok / BM), dim3(512), 51200, stream,
                       mh, img, br, bn, eps, out_probs, out_idx, cnt, list);
    hipLaunchKernelGGL(refine_fp64, dim3(2048), dim3(256), 0, stream,
                       mh, Wr, br, Wn, bn, eps, out_probs, out_idx, cnt, list);
}